// Round 8
// baseline (1180.077 us; speedup 1.0000x reference)
//
#include <hip/hip_runtime.h>
#include <math.h>

// SoftclDiceLoss on (B,C,D,H,W) = (2,1,64,256,256) float32.
// R8: no x-staging. cross8 reads x directly from global (L1/L2-resident);
// only mp lives in LDS (ring 2, 20.7 KB -> high occupancy). Both
// skeletonization chains (tgt and pred) run in the SAME dispatches.
//   mp[q]  = 7-point cross min of x      (global reads -> LDS write)
//   hw9[q] = 3x3 HW-max of mp[q]         (LDS reads -> registers, D-ring of 3)
//   out[d=q-1] = relu(x - (max(hw9[d-1..d+1]) - mp_center[d]))
// Block: 256 thr = 32 rows x 8 col-jobs of 8 floats; tile 32x64; CD=8.
// Per tensor: 2b x 8 chunks x 8x4 tiles = 512 blocks; merged grid 1024.

constexpr int B  = 2;
constexpr int D  = 64;
constexpr int H  = 256;
constexpr int W  = 256;
constexpr int HW = H * W;           // 65536
constexpr int NV = B * D * H * W;   // 8388608

constexpr int CD = 8;               // D-chunk per block
constexpr int MS = 76;              // smp row stride floats (19 quads, odd)
constexpr int MH = 34;              // mp rows (halo 1)
// mp float f of row mr <-> (gh, gw) = (h0-1+mr, w0-4+f)
// output row r col 8k+j (j=0..7) <-> mp row r+1, floats 8k+4..8k+11

__device__ __forceinline__ float4 vmin4(float4 a, float4 b) {
    return make_float4(fminf(a.x,b.x), fminf(a.y,b.y), fminf(a.z,b.z), fminf(a.w,b.w));
}
__device__ __forceinline__ float4 vmax4(float4 a, float4 b) {
    return make_float4(fmaxf(a.x,b.x), fmaxf(a.y,b.y), fmaxf(a.z,b.z), fmaxf(a.w,b.w));
}
__device__ __forceinline__ float4 sh1(float4 a, float4 b) { return make_float4(a.y,a.z,a.w,b.x); }
__device__ __forceinline__ float4 sh3(float4 a, float4 b) { return make_float4(a.w,b.x,b.y,b.z); }

__global__ __launch_bounds__(256) void prep_kernel(const float* __restrict__ logits,
                                                   const float* __restrict__ target,
                                                   const float* __restrict__ mask,
                                                   float* __restrict__ pred,
                                                   float* __restrict__ tgt) {
    int i = (blockIdx.x * 256 + threadIdx.x) * 4;
    float4 lg = *(const float4*)(logits + i);
    float4 tg = *(const float4*)(target + i);
    float4 mk = *(const float4*)(mask + i);
    float4 p, t;
    p.x = (1.0f/(1.0f+expf(-lg.x)))*mk.x;  t.x = tg.x*mk.x;
    p.y = (1.0f/(1.0f+expf(-lg.y)))*mk.y;  t.y = tg.y*mk.y;
    p.z = (1.0f/(1.0f+expf(-lg.z)))*mk.z;  t.z = tg.z*mk.z;
    p.w = (1.0f/(1.0f+expf(-lg.w)))*mk.w;  t.w = tg.w*mk.w;
    *(float4*)(pred + i) = p;
    *(float4*)(tgt + i)  = t;
}

template <bool FINAL>
__global__ __launch_bounds__(256) void skel_iter_kernel(
        const float* __restrict__ in0, float* __restrict__ out0,
        const float* __restrict__ oth0, double* __restrict__ acc0,
        const float* __restrict__ in1, float* __restrict__ out1,
        const float* __restrict__ oth1, double* __restrict__ acc1) {
    alignas(16) __shared__ float smp[2][MH * MS];   // 20.7 KB

    // XCD-chunked swizzle (contiguous logical chunk per XCD)
    int cpx = gridDim.x >> 3;
    int hwb = blockIdx.x;
    int bx  = (hwb & 7) * cpx + (hwb >> 3);

    int t   = bx >> 9;                 // tensor select (0 when grid=512)
    int bt  = bx & 511;
    int w0  = (bt & 3) * 64;
    int h0  = ((bt >> 2) & 7) * 32;
    int gd0 = ((bt >> 5) & 7) * CD;
    int b   = (bt >> 8) & 1;

    const float* xin  = t ? in1  : in0;
    float*       xout = t ? out1 : out0;
    const float* oth  = t ? oth1 : oth0;
    double*      accp = t ? acc1 : acc0;

    int tid = threadIdx.x;
    int r   = tid >> 3;        // 0..31 output row
    int k   = tid & 7;         // 0..7  8-float col job (cols 8k..8k+7)

    const float* xb  = xin + b * (D * HW);
    float*       ob  = xout ? (xout + b * (D * HW)) : nullptr;
    const float* otb = oth + b * (D * HW);

    const float4 inf4  = make_float4( INFINITY,  INFINITY,  INFINITY,  INFINITY);
    const float4 ninf4 = make_float4(-INFINITY, -INFINITY, -INFINITY, -INFINITY);

    // quad fetch: gq = global quad index (gw = 4*gq); pl==null -> plane OOB
    auto fetchg = [&](const float* pl, int gh, int gq) -> float4 {
        if (pl && (unsigned)gh < (unsigned)H && (unsigned)gq < 64u)
            return *(const float4*)(pl + gh * W + 4 * gq);
        return inf4;
    };

    // 7-point cross min for mp floats 8mk..8mk+7 of mp row mr (12 global reads)
    auto cross8 = [&](const float* pm, const float* pc, const float* pp,
                      int mr, int mk, float4& lo, float4& hi) {
        int gh  = h0 - 1 + mr;
        int gq0 = (w0 >> 2) + 2 * mk - 1;   // quad of mp float 8mk
        float4 Gm1 = fetchg(pc, gh, gq0 - 1);
        float4 G0  = fetchg(pc, gh, gq0);
        float4 G1  = fetchg(pc, gh, gq0 + 1);
        float4 G2  = fetchg(pc, gh, gq0 + 2);
        lo = vmin4(vmin4(sh3(Gm1, G0), G0), sh1(G0, G1));
        hi = vmin4(vmin4(sh3(G0, G1), G1), sh1(G1, G2));
        lo = vmin4(lo, fetchg(pc, gh - 1, gq0));
        hi = vmin4(hi, fetchg(pc, gh - 1, gq0 + 1));
        lo = vmin4(lo, fetchg(pc, gh + 1, gq0));
        hi = vmin4(hi, fetchg(pc, gh + 1, gq0 + 1));
        lo = vmin4(lo, fetchg(pm, gh, gq0));
        hi = vmin4(hi, fetchg(pm, gh, gq0 + 1));
        lo = vmin4(lo, fetchg(pp, gh, gq0));
        hi = vmin4(hi, fetchg(pp, gh, gq0 + 1));
        if ((unsigned)gh >= (unsigned)H) { lo = ninf4; hi = ninf4; return; }
        int wb = w0 - 4 + 8 * mk;          // OOB cols -> -INF (max ignores)
        lo.x = ((unsigned)(wb + 0) < (unsigned)W) ? lo.x : -INFINITY;
        lo.y = ((unsigned)(wb + 1) < (unsigned)W) ? lo.y : -INFINITY;
        lo.z = ((unsigned)(wb + 2) < (unsigned)W) ? lo.z : -INFINITY;
        lo.w = ((unsigned)(wb + 3) < (unsigned)W) ? lo.w : -INFINITY;
        hi.x = ((unsigned)(wb + 4) < (unsigned)W) ? hi.x : -INFINITY;
        hi.y = ((unsigned)(wb + 5) < (unsigned)W) ? hi.y : -INFINITY;
        hi.z = ((unsigned)(wb + 6) < (unsigned)W) ? hi.z : -INFINITY;
        hi.w = ((unsigned)(wb + 7) < (unsigned)W) ? hi.w : -INFINITY;
    };

    float4 h2lo = ninf4, h2hi = ninf4;   // hw9 ring: plane q-2
    float4 h1lo = ninf4, h1hi = ninf4;   //           plane q-1
    float4 m1lo = ninf4, m1hi = ninf4;   // mp centers of plane q-1
    double s0 = 0.0, s1 = 0.0;

    for (int q = gd0 - 1; q <= gd0 + CD; ++q) {
        bool qv = (q >= 0 && q < D);
        float* mp = smp[q & 1];
        if (qv) {
            const float* pc = xb + q * HW;
            const float* pm = (q - 1 >= 0) ? xb + (q - 1) * HW : nullptr;
            const float* pp = (q + 1 < D)  ? xb + (q + 1) * HW : nullptr;
            float4 lo, hi;
            cross8(pm, pc, pp, r, k, lo, hi);
            *(float4*)&mp[r * MS + 8 * k]     = lo;
            *(float4*)&mp[r * MS + 8 * k + 4] = hi;
            if (tid < 50) {            // halo jobs: col-quad 8 + rows 32,33
                int mr2, mk2;
                if (tid < 34) { mr2 = tid; mk2 = 8; }
                else          { int u = tid - 34; mr2 = 32 + (u >> 3); mk2 = u & 7; }
                cross8(pm, pc, pp, mr2, mk2, lo, hi);
                *(float4*)&mp[mr2 * MS + 8 * mk2]     = lo;
                *(float4*)&mp[mr2 * MS + 8 * mk2 + 4] = hi;
            }
        }

        // preload x center for out[d=q-1] before the barrier (global, in-bounds)
        int d = q - 1;
        bool dv = (d >= gd0);
        float4 xvlo = inf4, xvhi = inf4, ovlo = inf4, ovhi = inf4;
        if (dv) {
            const float* pd = xb + d * HW;
            int go = (h0 + r) * W + (w0 + 8 * k);
            xvlo = *(const float4*)(pd + go);
            xvhi = *(const float4*)(pd + go + 4);
            if constexpr (FINAL) {
                ovlo = *(const float4*)(otb + d * HW + go);
                ovhi = *(const float4*)(otb + d * HW + go + 4);
            }
        }

        __syncthreads();   // mp[q] visible; also protects next iter's WAR

        // hw9[q]: 3x3 HW max of mp[q]; smp rows r..r+2, quads 2k..2k+3
        float4 hclo, hchi, mclo, mchi;
        if (qv) {
            const float* m = smp[q & 1];
            int base = r * MS + 8 * k;
            float4 a0, a1, a2, a3, t0lo, t0hi, t1lo, t1hi, t2lo, t2hi;
            a0 = *(const float4*)&m[base];      a1 = *(const float4*)&m[base + 4];
            a2 = *(const float4*)&m[base + 8];  a3 = *(const float4*)&m[base + 12];
            t0lo = vmax4(vmax4(sh3(a0, a1), a1), sh1(a1, a2));
            t0hi = vmax4(vmax4(sh3(a1, a2), a2), sh1(a2, a3));
            base += MS;
            a0 = *(const float4*)&m[base];      a1 = *(const float4*)&m[base + 4];
            a2 = *(const float4*)&m[base + 8];  a3 = *(const float4*)&m[base + 12];
            t1lo = vmax4(vmax4(sh3(a0, a1), a1), sh1(a1, a2));
            t1hi = vmax4(vmax4(sh3(a1, a2), a2), sh1(a2, a3));
            mclo = a1; mchi = a2;
            base += MS;
            a0 = *(const float4*)&m[base];      a1 = *(const float4*)&m[base + 4];
            a2 = *(const float4*)&m[base + 8];  a3 = *(const float4*)&m[base + 12];
            t2lo = vmax4(vmax4(sh3(a0, a1), a1), sh1(a1, a2));
            t2hi = vmax4(vmax4(sh3(a1, a2), a2), sh1(a2, a3));
            hclo = vmax4(t0lo, vmax4(t1lo, t2lo));
            hchi = vmax4(t0hi, vmax4(t1hi, t2hi));
        } else { hclo = hchi = ninf4; mclo = mchi = ninf4; }

        // out[d] = relu(x - (max27 - mp_center))
        if (dv) {
            float4 mxlo = vmax4(h2lo, vmax4(h1lo, hclo));
            float4 mxhi = vmax4(h2hi, vmax4(h1hi, hchi));
            float4 rlo, rhi;
            rlo.x = fmaxf(xvlo.x - (mxlo.x - m1lo.x), 0.0f);
            rlo.y = fmaxf(xvlo.y - (mxlo.y - m1lo.y), 0.0f);
            rlo.z = fmaxf(xvlo.z - (mxlo.z - m1lo.z), 0.0f);
            rlo.w = fmaxf(xvlo.w - (mxlo.w - m1lo.w), 0.0f);
            rhi.x = fmaxf(xvhi.x - (mxhi.x - m1hi.x), 0.0f);
            rhi.y = fmaxf(xvhi.y - (mxhi.y - m1hi.y), 0.0f);
            rhi.z = fmaxf(xvhi.z - (mxhi.z - m1hi.z), 0.0f);
            rhi.w = fmaxf(xvhi.w - (mxhi.w - m1hi.w), 0.0f);
            if constexpr (FINAL) {
                s0 += (double)(rlo.x * ovlo.x) + (double)(rlo.y * ovlo.y)
                    + (double)(rlo.z * ovlo.z) + (double)(rlo.w * ovlo.w)
                    + (double)(rhi.x * ovhi.x) + (double)(rhi.y * ovhi.y)
                    + (double)(rhi.z * ovhi.z) + (double)(rhi.w * ovhi.w);
                s1 += (double)rlo.x + (double)rlo.y + (double)rlo.z + (double)rlo.w
                    + (double)rhi.x + (double)rhi.y + (double)rhi.z + (double)rhi.w;
            } else {
                long off = (long)d * HW + (h0 + r) * W + (w0 + 8 * k);
                *(float4*)(ob + off)     = rlo;
                *(float4*)(ob + off + 4) = rhi;
            }
        }
        h2lo = h1lo; h1lo = hclo;  h2hi = h1hi; h1hi = hchi;
        m1lo = mclo; m1hi = mchi;
    }

    if constexpr (FINAL) {
        for (int off = 32; off > 0; off >>= 1) {
            s0 += __shfl_down(s0, off, 64);
            s1 += __shfl_down(s1, off, 64);
        }
        if ((tid & 63) == 0) {
            atomicAdd(&accp[0], s0);
            atomicAdd(&accp[1], s1);
        }
    }
}

__global__ void final_kernel(const double* __restrict__ acc, float* __restrict__ out) {
    double clrecall = (acc[0] + 1e-12) / (acc[1] + 1e-12);
    double clacc    = (acc[2] + 1e-12) / (acc[3] + 1e-12);
    double cldice   = 2.0 * clrecall * clacc / (clrecall + clacc + 1e-12);
    out[0] = (float)(1.0 - cldice);
}

extern "C" void kernel_launch(void* const* d_in, const int* in_sizes, int n_in,
                              void* d_out, int out_size, void* d_ws, size_t ws_size,
                              hipStream_t stream) {
    const float* logits = (const float*)d_in[0];
    const float* target = (const float*)d_in[1];
    const float* mask   = (const float*)d_in[2];
    float* out = (float*)d_out;

    float* pred = (float*)d_ws;
    float* tgt  = pred + NV;
    float* A0   = tgt + NV;
    float* B0   = A0 + NV;

    bool big = ws_size >= (size_t)6 * NV * 4 + 64;
    float* A1   = big ? (B0 + NV)      : A0;
    float* B1   = big ? (A1 + NV)      : B0;
    double* acc = big ? (double*)(B1 + NV) : (double*)(B0 + NV);

    hipMemsetAsync(acc, 0, 4 * sizeof(double), stream);

    dim3 blk(256);
    prep_kernel<<<dim3(NV / 1024), blk, 0, stream>>>(logits, target, mask, pred, tgt);

    if (big) {
        dim3 g(1024);   // both tensors per dispatch
        skel_iter_kernel<false><<<g, blk, 0, stream>>>(tgt, A0, pred, acc, pred, A1, tgt, acc + 2);
        skel_iter_kernel<false><<<g, blk, 0, stream>>>(A0, B0, pred, acc, A1, B1, tgt, acc + 2);
        skel_iter_kernel<false><<<g, blk, 0, stream>>>(B0, A0, pred, acc, B1, A1, tgt, acc + 2);
        skel_iter_kernel<false><<<g, blk, 0, stream>>>(A0, B0, pred, acc, A1, B1, tgt, acc + 2);
        skel_iter_kernel<true ><<<g, blk, 0, stream>>>(B0, nullptr, pred, acc, B1, nullptr, tgt, acc + 2);
    } else {
        dim3 g(512);    // sequential fallback (t = 0 always)
        skel_iter_kernel<false><<<g, blk, 0, stream>>>(tgt, A0, pred, acc, tgt, A0, pred, acc);
        skel_iter_kernel<false><<<g, blk, 0, stream>>>(A0, B0, pred, acc, A0, B0, pred, acc);
        skel_iter_kernel<false><<<g, blk, 0, stream>>>(B0, A0, pred, acc, B0, A0, pred, acc);
        skel_iter_kernel<false><<<g, blk, 0, stream>>>(A0, B0, pred, acc, A0, B0, pred, acc);
        skel_iter_kernel<true ><<<g, blk, 0, stream>>>(B0, nullptr, pred, acc, B0, nullptr, pred, acc);
        skel_iter_kernel<false><<<g, blk, 0, stream>>>(pred, A0, tgt, acc + 2, pred, A0, tgt, acc + 2);
        skel_iter_kernel<false><<<g, blk, 0, stream>>>(A0, B0, tgt, acc + 2, A0, B0, tgt, acc + 2);
        skel_iter_kernel<false><<<g, blk, 0, stream>>>(B0, A0, tgt, acc + 2, B0, A0, tgt, acc + 2);
        skel_iter_kernel<false><<<g, blk, 0, stream>>>(A0, B0, tgt, acc + 2, A0, B0, tgt, acc + 2);
        skel_iter_kernel<true ><<<g, blk, 0, stream>>>(B0, nullptr, tgt, acc + 2, B0, nullptr, tgt, acc + 2);
    }

    final_kernel<<<1, 1, 0, stream>>>(acc, out);
}

// Round 9
// 450.550 us; speedup vs baseline: 2.6192x; 2.6192x over previous
//
#include <hip/hip_runtime.h>
#include <math.h>

// SoftclDiceLoss on (B,C,D,H,W) = (2,1,64,256,256) float32.
// R9: register-separable skeletonize iteration.
//   Each thread owns output row r, cols 8k..8k+7 and computes mp row r+1
//   (its own center row) fully in registers from the LDS x ring (12 b128
//   reads). W-edge mp values come from lane shuffles (+in-thread ext for
//   k=0/7). The 3-wide W rowmax is written to LDS (ring 2); the 3x3 HW max
//   needs only 4 aligned LDS reads (rows r, r+2) + the register row r+1.
//   mp-center and hw9 ring over D live in registers. mp LDS plane: GONE.
//   out[d=q-1] = relu(x - (max(hw9[d-1..d+1]) - mp_center[d]))
// x ring 3 (2-barrier hazard-free), staging prefetch depth = 1 full iter.
// Block 256 = 32 rows x 8 col-jobs; tile 32x64; CD=8; grid 512 (2/CU,
// capacity 3 at 50.1 KB LDS). Sequential chains (L3-friendly 4-buffer set).

constexpr int Bn = 2;
constexpr int D  = 64;
constexpr int H  = 256;
constexpr int W  = 256;
constexpr int HW = H * W;           // 65536
constexpr int NV = Bn * D * H * W;  // 8388608

constexpr int CD  = 8;              // D-chunk per block
constexpr int XSF = 76;             // x LDS row stride (19 quads, odd)
constexpr int RSF = 68;             // rowmax LDS row stride (17 quads, odd)
// x plane: 36 rows (gh = h0-2+row), 18 quads (gw = w0-4+4q), f = gw-w0+4
// rowmax:  34 rows (mp row mr, gh = h0-1+mr), cols 0..63 (= output cols)

__device__ __forceinline__ float4 vmin4(float4 a, float4 b) {
    return make_float4(fminf(a.x,b.x), fminf(a.y,b.y), fminf(a.z,b.z), fminf(a.w,b.w));
}
__device__ __forceinline__ float4 vmax4(float4 a, float4 b) {
    return make_float4(fmaxf(a.x,b.x), fmaxf(a.y,b.y), fmaxf(a.z,b.z), fmaxf(a.w,b.w));
}
__device__ __forceinline__ float4 sh1(float4 a, float4 b) { return make_float4(a.y,a.z,a.w,b.x); }
__device__ __forceinline__ float4 sh3(float4 a, float4 b) { return make_float4(a.w,b.x,b.y,b.z); }

__global__ __launch_bounds__(256) void prep_kernel(const float* __restrict__ logits,
                                                   const float* __restrict__ target,
                                                   const float* __restrict__ mask,
                                                   float* __restrict__ pred,
                                                   float* __restrict__ tgt) {
    int i = (blockIdx.x * 256 + threadIdx.x) * 4;
    float4 lg = *(const float4*)(logits + i);
    float4 tg = *(const float4*)(target + i);
    float4 mk = *(const float4*)(mask + i);
    float4 p, t;
    p.x = (1.0f/(1.0f+expf(-lg.x)))*mk.x;  t.x = tg.x*mk.x;
    p.y = (1.0f/(1.0f+expf(-lg.y)))*mk.y;  t.y = tg.y*mk.y;
    p.z = (1.0f/(1.0f+expf(-lg.z)))*mk.z;  t.z = tg.z*mk.z;
    p.w = (1.0f/(1.0f+expf(-lg.w)))*mk.w;  t.w = tg.w*mk.w;
    *(float4*)(pred + i) = p;
    *(float4*)(tgt + i)  = t;
}

template <bool FINAL>
__global__ __launch_bounds__(256) void skel_iter_kernel(const float* __restrict__ xin,
                                                        float* __restrict__ xout,
                                                        const float* __restrict__ other,
                                                        double* __restrict__ acc) {
    __shared__ float sx[3][36 * XSF];   // x ring of 3 (32.1 KB)
    __shared__ float srm[2][34 * RSF];  // rowmax ring of 2 (18.1 KB)

    // XCD-chunked swizzle (64 consecutive logical blocks per XCD)
    int hwb = blockIdx.x;
    int bx  = (hwb & 7) * 64 + (hwb >> 3);

    int w0  = (bx & 3) * 64;
    int h0  = ((bx >> 2) & 7) * 32;
    int gd0 = ((bx >> 5) & 7) * CD;
    int b   = bx >> 8;

    int tid = threadIdx.x;
    int r   = tid >> 3;   // 0..31 output row
    int k   = tid & 7;    // 0..7  8-col job

    const float* xb  = xin + b * (D * HW);
    float*       ob  = xout ? (xout + b * (D * HW)) : nullptr;
    const float* otb = other + b * (D * HW);

    const float4 INF4  = make_float4( INFINITY,  INFINITY,  INFINITY,  INFINITY);
    const float4 NINF4 = make_float4(-INFINITY, -INFINITY, -INFINITY, -INFINITY);

    // staging map: 648 quads (36 rows x 18), 3 rounds of 256
    int j1 = tid + 256, j2 = tid + 512;
    int sr0 = tid / 18, sq0 = tid - sr0 * 18;
    int sr1 = j1 / 18,  sq1 = j1 - sr1 * 18;
    int sr2 = j2 / 18,  sq2 = j2 - sr2 * 18;
    bool has2 = (j2 < 648);

    float4 Pa, Pb, Pc;   // pending plane (issued one iteration ago)
    auto issue = [&](int p) {
        if (p < 0 || p >= D) { Pa = Pb = Pc = INF4; return; }
        const float* pl = xb + p * HW;
        auto f = [&](int row, int qd) -> float4 {
            int gh = h0 - 2 + row;
            int gw = w0 - 4 + 4 * qd;     // multiple of 4: quad fully in or out
            if ((unsigned)gh < (unsigned)H && (unsigned)gw < (unsigned)W)
                return *(const float4*)(pl + gh * W + gw);
            return INF4;
        };
        Pa = f(sr0, sq0);
        Pb = f(sr1, sq1);
        Pc = has2 ? f(sr2, sq2) : INF4;
    };
    auto commit = [&](int p) {
        float* dst = sx[(p + 33) % 3];
        *(float4*)&dst[sr0 * XSF + 4 * sq0] = Pa;
        *(float4*)&dst[sr1 * XSF + 4 * sq1] = Pb;
        if (has2) *(float4*)&dst[sr2 * XSF + 4 * sq2] = Pc;
    };

    // Prologue: x[gd0-2], x[gd0-1] resident; x[gd0] pending for first commit.
    issue(gd0 - 2); commit(gd0 - 2);
    issue(gd0 - 1); commit(gd0 - 1);
    issue(gd0);

    float4 h1lo=NINF4, h1hi=NINF4, h2lo=NINF4, h2hi=NINF4;  // hw9 D-ring
    float4 m1lo=NINF4, m1hi=NINF4;                          // mp center of q-1
    double s0 = 0.0, s1 = 0.0;

    for (int q = gd0 - 1; q <= gd0 + CD; ++q) {
        // ---- phase A: commit x[q+1] (pending), issue x[q+2] ----
        // commit overwrites x[q-2]: last read iter q-1 phase B, sep by B2_{q-1}.
        commit(q + 1);
        if (q + 2 <= gd0 + CD + 1) issue(q + 2);
        __syncthreads();                                   // B1

        bool qv = (q >= 0 && q < D);
        int  d  = q - 1;
        bool dv = (d >= gd0);

        // ---- phase B: mp row r+1 in regs, rowmax -> LDS ----
        float4 lo = NINF4, hi = NINF4, rmlo = NINF4, rmhi = NINF4;
        if (qv) {
            const float* xq = sx[(q + 33) % 3];
            const float* xm = sx[(q + 32) % 3];
            const float* xp = sx[(q + 34) % 3];
            {
                const float* rc  = &xq[(r + 2) * XSF + 8 * k];
                const float* ru  = &xq[(r + 1) * XSF + 8 * k];
                const float* rd  = &xq[(r + 3) * XSF + 8 * k];
                const float* rm_ = &xm[(r + 2) * XSF + 8 * k];
                const float* rp_ = &xp[(r + 2) * XSF + 8 * k];
                float4 X0 = *(const float4*)rc,        X1 = *(const float4*)(rc + 4),
                       X2 = *(const float4*)(rc + 8),  X3 = *(const float4*)(rc + 12);
                float4 U1 = *(const float4*)(ru + 4),  U2 = *(const float4*)(ru + 8);
                float4 Dn1= *(const float4*)(rd + 4),  Dn2= *(const float4*)(rd + 8);
                float4 M1 = *(const float4*)(rm_ + 4), M2 = *(const float4*)(rm_ + 8);
                float4 P1 = *(const float4*)(rp_ + 4), P2 = *(const float4*)(rp_ + 8);
                // 7-point cross min, e0..7 (cols w0+8k..8k+7, all interior)
                lo = vmin4(vmin4(sh3(X0, X1), X1), sh1(X1, X2));
                lo = vmin4(lo, vmin4(vmin4(U1, Dn1), vmin4(M1, P1)));
                hi = vmin4(vmin4(sh3(X1, X2), X2), sh1(X2, X3));
                hi = vmin4(hi, vmin4(vmin4(U2, Dn2), vmin4(M2, P2)));
                // W-edge mp values: shuffles (all lanes), in-thread ext for k=0/7
                float eL = __shfl_up(hi.w, 1);
                float eR = __shfl_down(lo.x, 1);
                if (k == 0) {
                    eL = -INFINITY;
                    if (w0 > 0) {
                        float w3 = fminf(fminf(X0.z, X0.w), X1.x);
                        eL = fminf(fminf(w3, fminf(ru[3], rd[3])),
                                   fminf(rm_[3], rp_[3]));
                    }
                }
                if (k == 7) {
                    eR = -INFINITY;
                    if (w0 + 64 < W) {
                        float w3 = fminf(fminf(X2.w, X3.x), X3.y);
                        eR = fminf(fminf(w3, fminf(ru[12], rd[12])),
                                   fminf(rm_[12], rp_[12]));
                    }
                }
                rmlo = vmax4(vmax4(make_float4(eL, lo.x, lo.y, lo.z), lo),
                             make_float4(lo.y, lo.z, lo.w, hi.x));
                rmhi = vmax4(vmax4(make_float4(lo.w, hi.x, hi.y, hi.z), hi),
                             make_float4(hi.y, hi.z, hi.w, eR));
                float* rw = &srm[q & 1][(r + 1) * RSF + 8 * k];
                *(float4*)rw       = rmlo;
                *(float4*)(rw + 4) = rmhi;
            }
            // halo rows 0 and 33: fully in-thread (LDS-only, self-contained ext)
            if (tid < 16) {
                int mr2 = (tid >> 3) ? 33 : 0;
                int k2  = tid & 7;
                int gh2 = h0 - 1 + mr2;
                float4 hlo = NINF4, hhi = NINF4;
                if ((unsigned)gh2 < (unsigned)H) {
                    int xr2 = mr2 + 1;
                    const float* rc  = &xq[xr2 * XSF + 8 * k2];
                    const float* ru  = &xq[(xr2 - 1) * XSF + 8 * k2];
                    const float* rd  = &xq[(xr2 + 1) * XSF + 8 * k2];
                    const float* rm_ = &xm[xr2 * XSF + 8 * k2];
                    const float* rp_ = &xp[xr2 * XSF + 8 * k2];
                    float4 X0 = *(const float4*)rc,        X1 = *(const float4*)(rc + 4),
                           X2 = *(const float4*)(rc + 8),  X3 = *(const float4*)(rc + 12);
                    float4 U1 = *(const float4*)(ru + 4),  U2 = *(const float4*)(ru + 8);
                    float4 Dn1= *(const float4*)(rd + 4),  Dn2= *(const float4*)(rd + 8);
                    float4 M1 = *(const float4*)(rm_ + 4), M2 = *(const float4*)(rm_ + 8);
                    float4 P1 = *(const float4*)(rp_ + 4), P2 = *(const float4*)(rp_ + 8);
                    float4 l2 = vmin4(vmin4(sh3(X0, X1), X1), sh1(X1, X2));
                    l2 = vmin4(l2, vmin4(vmin4(U1, Dn1), vmin4(M1, P1)));
                    float4 g2 = vmin4(vmin4(sh3(X1, X2), X2), sh1(X2, X3));
                    g2 = vmin4(g2, vmin4(vmin4(U2, Dn2), vmin4(M2, P2)));
                    float eL2 = -INFINITY, eR2 = -INFINITY;
                    if (w0 + 8 * k2 - 1 >= 0) {
                        float w3 = fminf(fminf(X0.z, X0.w), X1.x);
                        eL2 = fminf(fminf(w3, fminf(ru[3], rd[3])),
                                    fminf(rm_[3], rp_[3]));
                    }
                    if (w0 + 8 * k2 + 8 < W) {
                        float w3 = fminf(fminf(X2.w, X3.x), X3.y);
                        eR2 = fminf(fminf(w3, fminf(ru[12], rd[12])),
                                    fminf(rm_[12], rp_[12]));
                    }
                    hlo = vmax4(vmax4(make_float4(eL2, l2.x, l2.y, l2.z), l2),
                                make_float4(l2.y, l2.z, l2.w, g2.x));
                    hhi = vmax4(vmax4(make_float4(l2.w, g2.x, g2.y, g2.z), g2),
                                make_float4(g2.y, g2.z, g2.w, eR2));
                }
                float* hw = &srm[q & 1][mr2 * RSF + 8 * k2];
                *(float4*)hw       = hlo;
                *(float4*)(hw + 4) = hhi;
            }
        }

        // x center for out[d=q-1], read pre-B2 (slot q-1 overwritten only at
        // iter q+1 phase A, separated by this B2)
        float4 xvlo = INF4, xvhi = INF4;
        if (dv) {
            const float* xd = sx[(q + 32) % 3];
            xvlo = *(const float4*)&xd[(r + 2) * XSF + 8 * k + 4];
            xvhi = *(const float4*)&xd[(r + 2) * XSF + 8 * k + 8];
        }
        __syncthreads();                                   // B2

        // ---- phase C: hw9 (4 LDS reads + reg row) and output ----
        float4 hclo = NINF4, hchi = NINF4;
        if (qv) {
            const float* m = srm[q & 1];
            float4 a0 = *(const float4*)&m[r * RSF + 8 * k];
            float4 a1 = *(const float4*)&m[r * RSF + 8 * k + 4];
            float4 b0 = *(const float4*)&m[(r + 2) * RSF + 8 * k];
            float4 b1 = *(const float4*)&m[(r + 2) * RSF + 8 * k + 4];
            hclo = vmax4(vmax4(a0, rmlo), b0);
            hchi = vmax4(vmax4(a1, rmhi), b1);
        }

        if (dv) {
            float4 mxlo = vmax4(h2lo, vmax4(h1lo, hclo));
            float4 mxhi = vmax4(h2hi, vmax4(h1hi, hchi));
            float4 rlo, rhi;
            rlo.x = fmaxf(xvlo.x - (mxlo.x - m1lo.x), 0.0f);
            rlo.y = fmaxf(xvlo.y - (mxlo.y - m1lo.y), 0.0f);
            rlo.z = fmaxf(xvlo.z - (mxlo.z - m1lo.z), 0.0f);
            rlo.w = fmaxf(xvlo.w - (mxlo.w - m1lo.w), 0.0f);
            rhi.x = fmaxf(xvhi.x - (mxhi.x - m1hi.x), 0.0f);
            rhi.y = fmaxf(xvhi.y - (mxhi.y - m1hi.y), 0.0f);
            rhi.z = fmaxf(xvhi.z - (mxhi.z - m1hi.z), 0.0f);
            rhi.w = fmaxf(xvhi.w - (mxhi.w - m1hi.w), 0.0f);
            long off = (long)d * HW + (h0 + r) * W + (w0 + 8 * k);
            if constexpr (FINAL) {
                float4 o1 = *(const float4*)(otb + off);
                float4 o2 = *(const float4*)(otb + off + 4);
                s0 += (double)(rlo.x * o1.x) + (double)(rlo.y * o1.y)
                    + (double)(rlo.z * o1.z) + (double)(rlo.w * o1.w)
                    + (double)(rhi.x * o2.x) + (double)(rhi.y * o2.y)
                    + (double)(rhi.z * o2.z) + (double)(rhi.w * o2.w);
                s1 += (double)rlo.x + (double)rlo.y + (double)rlo.z + (double)rlo.w
                    + (double)rhi.x + (double)rhi.y + (double)rhi.z + (double)rhi.w;
            } else {
                *(float4*)(ob + off)     = rlo;
                *(float4*)(ob + off + 4) = rhi;
            }
        }
        h2lo = h1lo; h1lo = hclo;  h2hi = h1hi; h1hi = hchi;
        m1lo = lo;   m1hi = hi;
    }

    if constexpr (FINAL) {
        for (int off = 32; off > 0; off >>= 1) {
            s0 += __shfl_down(s0, off, 64);
            s1 += __shfl_down(s1, off, 64);
        }
        if ((tid & 63) == 0) {
            atomicAdd(&acc[0], s0);
            atomicAdd(&acc[1], s1);
        }
    }
}

__global__ void final_kernel(const double* __restrict__ acc, float* __restrict__ out) {
    double clrecall = (acc[0] + 1e-12) / (acc[1] + 1e-12);
    double clacc    = (acc[2] + 1e-12) / (acc[3] + 1e-12);
    double cldice   = 2.0 * clrecall * clacc / (clrecall + clacc + 1e-12);
    out[0] = (float)(1.0 - cldice);
}

extern "C" void kernel_launch(void* const* d_in, const int* in_sizes, int n_in,
                              void* d_out, int out_size, void* d_ws, size_t ws_size,
                              hipStream_t stream) {
    const float* logits = (const float*)d_in[0];
    const float* target = (const float*)d_in[1];
    const float* mask   = (const float*)d_in[2];
    float* out = (float*)d_out;

    // Workspace (floats): pred | tgt | xA | xB | acc(4 doubles)  (~134 MB: L3-friendly)
    float* pred = (float*)d_ws;
    float* tgt  = pred + NV;
    float* xA   = tgt + NV;
    float* xB   = xA + NV;
    double* acc = (double*)(xB + NV);

    hipMemsetAsync(acc, 0, 4 * sizeof(double), stream);

    dim3 blk(256);
    prep_kernel<<<dim3(NV / 1024), blk, 0, stream>>>(logits, target, mask, pred, tgt);

    dim3 sgrd(512);  // 2 b x 8 chunks x 8 h x 4 w tiles; 2 blocks/CU, all resident

    // skeletonize(tgt): tgt -> A -> B -> A -> B -> (fused reduce vs pred)
    skel_iter_kernel<false><<<sgrd, blk, 0, stream>>>(tgt, xA, pred, acc);
    skel_iter_kernel<false><<<sgrd, blk, 0, stream>>>(xA, xB, pred, acc);
    skel_iter_kernel<false><<<sgrd, blk, 0, stream>>>(xB, xA, pred, acc);
    skel_iter_kernel<false><<<sgrd, blk, 0, stream>>>(xA, xB, pred, acc);
    skel_iter_kernel<true ><<<sgrd, blk, 0, stream>>>(xB, nullptr, pred, acc);

    // skeletonize(pred): pred -> A -> B -> A -> B -> (fused reduce vs tgt)
    skel_iter_kernel<false><<<sgrd, blk, 0, stream>>>(pred, xA, tgt, acc + 2);
    skel_iter_kernel<false><<<sgrd, blk, 0, stream>>>(xA, xB, tgt, acc + 2);
    skel_iter_kernel<false><<<sgrd, blk, 0, stream>>>(xB, xA, tgt, acc + 2);
    skel_iter_kernel<false><<<sgrd, blk, 0, stream>>>(xA, xB, tgt, acc + 2);
    skel_iter_kernel<true ><<<sgrd, blk, 0, stream>>>(xB, nullptr, tgt, acc + 2);

    final_kernel<<<1, 1, 0, stream>>>(acc, out);
}

// Round 10
// 330.952 us; speedup vs baseline: 3.5657x; 1.3614x over previous
//
#include <hip/hip_runtime.h>
#include <math.h>

// SoftclDiceLoss on (B,C,D,H,W) = (2,1,64,256,256) float32.
// R10: single-barrier software-pipelined skeletonize; both chains merged
// per dispatch; CD=16.
// Per segment s (one __syncthreads at the END of each segment):
//   commit x[s+2] (pending regs) ; issue x[s+3]
//   B(s):  mp[s] row r+1 in regs (12 b128 reads), rowmax -> srm[s&1]
//   xc:    x center of plane s-1 -> regs (carried 1 segment)
//   H(s-1): hw9[s-1] = max(srm[s-1] rows r,r+2, register row)  [4 b128 reads]
//   C(s-2): out[d=s-2] = relu(xv - (max(hw9[d-1..d+1]) - mp_center[d]))
// Hazard audit (all cross-thread pairs separated by >=1 barrier):
//   commit x[s+2] -> slot (s+2)&3; last readers of that slot (plane s-2):
//     B(s-1) & xc(s-1) in segment s-1: one barrier between.         OK
//   B(s) reads slots (s-1,s,s+1)&3; commit writes (s+2)&3: disjoint. OK
//   srm[s&1] written in s; read by H in segment s+1: one barrier.    OK
//   H reads srm[(s-1)&1]; B writes srm[s&1]: different buffer.       OK
// Block 256 = 32 rows x 8 col-jobs (8 floats); tile 32x64; grid 512 =
// 2 tensors x 2b x 4 chunks x 8x4 tiles; LDS 60.8 KB -> 2 blocks/CU.

constexpr int Bn = 2;
constexpr int D  = 64;
constexpr int H  = 256;
constexpr int W  = 256;
constexpr int HW = H * W;           // 65536
constexpr int NV = Bn * D * H * W;  // 8388608

constexpr int CD  = 16;             // D-chunk per block
constexpr int XSF = 76;             // x LDS row stride (19 quads, odd)
constexpr int RSF = 68;             // rowmax LDS row stride (17 quads, odd)
// x plane: 36 rows (gh = h0-2+row), 18 quads (gw = w0-4+4q)
// rowmax:  34 rows (mp row mr, gh = h0-1+mr), cols = output cols w0..w0+63

__device__ __forceinline__ float4 vmin4(float4 a, float4 b) {
    return make_float4(fminf(a.x,b.x), fminf(a.y,b.y), fminf(a.z,b.z), fminf(a.w,b.w));
}
__device__ __forceinline__ float4 vmax4(float4 a, float4 b) {
    return make_float4(fmaxf(a.x,b.x), fmaxf(a.y,b.y), fmaxf(a.z,b.z), fmaxf(a.w,b.w));
}
__device__ __forceinline__ float4 sh1(float4 a, float4 b) { return make_float4(a.y,a.z,a.w,b.x); }
__device__ __forceinline__ float4 sh3(float4 a, float4 b) { return make_float4(a.w,b.x,b.y,b.z); }

__global__ __launch_bounds__(256) void prep_kernel(const float* __restrict__ logits,
                                                   const float* __restrict__ target,
                                                   const float* __restrict__ mask,
                                                   float* __restrict__ pred,
                                                   float* __restrict__ tgt) {
    int i = (blockIdx.x * 256 + threadIdx.x) * 4;
    float4 lg = *(const float4*)(logits + i);
    float4 tg = *(const float4*)(target + i);
    float4 mk = *(const float4*)(mask + i);
    float4 p, t;
    p.x = (1.0f/(1.0f+expf(-lg.x)))*mk.x;  t.x = tg.x*mk.x;
    p.y = (1.0f/(1.0f+expf(-lg.y)))*mk.y;  t.y = tg.y*mk.y;
    p.z = (1.0f/(1.0f+expf(-lg.z)))*mk.z;  t.z = tg.z*mk.z;
    p.w = (1.0f/(1.0f+expf(-lg.w)))*mk.w;  t.w = tg.w*mk.w;
    *(float4*)(pred + i) = p;
    *(float4*)(tgt + i)  = t;
}

template <bool FINAL>
__global__ __launch_bounds__(256) void skel_iter_kernel(
        const float* __restrict__ in0, float* __restrict__ out0,
        const float* __restrict__ oth0, double* __restrict__ acc0,
        const float* __restrict__ in1, float* __restrict__ out1,
        const float* __restrict__ oth1, double* __restrict__ acc1) {
    __shared__ float sx[4][36 * XSF];   // x ring of 4 (43.8 KB)
    __shared__ float srm[2][34 * RSF];  // rowmax ring of 2 (18.5 KB)

    // XCD-chunked swizzle
    int cpx = gridDim.x >> 3;
    int hwb = blockIdx.x;
    int bx  = (hwb & 7) * cpx + (hwb >> 3);

    int t   = bx >> 8;                 // tensor select (0 when grid=256)
    int bt  = bx & 255;
    int w0  = (bt & 3) * 64;
    int h0  = ((bt >> 2) & 7) * 32;
    int gd0 = ((bt >> 5) & 3) * CD;
    int b   = (bt >> 7) & 1;

    const float* xin  = t ? in1  : in0;
    float*       xout = t ? out1 : out0;
    const float* oth  = t ? oth1 : oth0;
    double*      accp = t ? acc1 : acc0;

    int tid = threadIdx.x;
    int r   = tid >> 3;   // 0..31 output row
    int k   = tid & 7;    // 0..7  8-col job

    const float* xb  = xin + b * (D * HW);
    float*       ob  = xout ? (xout + b * (D * HW)) : nullptr;
    const float* otb = oth + b * (D * HW);

    const float4 INF4  = make_float4( INFINITY,  INFINITY,  INFINITY,  INFINITY);
    const float4 NINF4 = make_float4(-INFINITY, -INFINITY, -INFINITY, -INFINITY);

    // staging map: 648 quads (36 rows x 18), 3 rounds of 256
    int j1 = tid + 256, j2 = tid + 512;
    int sr0 = tid / 18, sq0 = tid - sr0 * 18;
    int sr1 = j1 / 18,  sq1 = j1 - sr1 * 18;
    int sr2 = j2 / 18,  sq2 = j2 - sr2 * 18;
    bool has2 = (j2 < 648);

    float4 Pa, Pb, Pc;   // pending plane
    auto issue = [&](int p) {
        if (p < 0 || p >= D) { Pa = Pb = Pc = INF4; return; }
        const float* pl = xb + p * HW;
        auto f = [&](int row, int qd) -> float4 {
            int gh = h0 - 2 + row;
            int gw = w0 - 4 + 4 * qd;
            if ((unsigned)gh < (unsigned)H && (unsigned)gw < (unsigned)W)
                return *(const float4*)(pl + gh * W + gw);
            return INF4;
        };
        Pa = f(sr0, sq0);
        Pb = f(sr1, sq1);
        Pc = has2 ? f(sr2, sq2) : INF4;
    };
    auto commitv = [&](int p, float4 va, float4 vb, float4 vc) {
        float* dst = sx[(p + 4) & 3];
        *(float4*)&dst[sr0 * XSF + 4 * sq0] = va;
        *(float4*)&dst[sr1 * XSF + 4 * sq1] = vb;
        if (has2) *(float4*)&dst[sr2 * XSF + 4 * sq2] = vc;
    };

    // Prologue: planes gd0-2..gd0 resident; x[gd0+1] pending.
    issue(gd0 - 2); commitv(gd0 - 2, Pa, Pb, Pc);
    issue(gd0 - 1); commitv(gd0 - 1, Pa, Pb, Pc);
    issue(gd0);     commitv(gd0,     Pa, Pb, Pc);
    issue(gd0 + 1);
    __syncthreads();

    float4 h1lo=NINF4, h1hi=NINF4, h2lo=NINF4, h2hi=NINF4;  // hw9 D-ring
    float4 p1lo=NINF4, p1hi=NINF4, p2lo=NINF4, p2hi=NINF4;  // mp centers
    float4 rmplo=NINF4, rmphi=NINF4;                        // reg rowmax of s-1
    float4 xplo=INF4, xphi=INF4;                            // x center of s-2
    double s0 = 0.0, s1 = 0.0;

    for (int s = gd0 - 1; s <= gd0 + CD + 1; ++s) {
        // ---- staging: commit x[s+2] (captured), issue x[s+3] ----
        float4 Ta = Pa, Tb = Pb, Tc = Pc;
        if (s + 3 <= gd0 + CD + 1) issue(s + 3);
        if (s + 2 <= gd0 + CD + 1) commitv(s + 2, Ta, Tb, Tc);

        // ---- B(s): mp row r+1 in regs, rowmax -> srm[s&1] ----
        bool sv = (s >= 0 && s < D && s <= gd0 + CD);
        float4 lo = NINF4, hi = NINF4, rmlo = NINF4, rmhi = NINF4;
        if (sv) {
            const float* xq = sx[(s + 4) & 3];
            const float* xm = sx[(s + 3) & 3];
            const float* xp = sx[(s + 5) & 3];
            {
                const float* rc  = &xq[(r + 2) * XSF + 8 * k];
                const float* ru  = &xq[(r + 1) * XSF + 8 * k];
                const float* rd  = &xq[(r + 3) * XSF + 8 * k];
                const float* rm_ = &xm[(r + 2) * XSF + 8 * k];
                const float* rp_ = &xp[(r + 2) * XSF + 8 * k];
                float4 X0 = *(const float4*)rc,        X1 = *(const float4*)(rc + 4),
                       X2 = *(const float4*)(rc + 8),  X3 = *(const float4*)(rc + 12);
                float4 U1 = *(const float4*)(ru + 4),  U2 = *(const float4*)(ru + 8);
                float4 Dn1= *(const float4*)(rd + 4),  Dn2= *(const float4*)(rd + 8);
                float4 M1 = *(const float4*)(rm_ + 4), M2 = *(const float4*)(rm_ + 8);
                float4 P1 = *(const float4*)(rp_ + 4), P2 = *(const float4*)(rp_ + 8);
                lo = vmin4(vmin4(sh3(X0, X1), X1), sh1(X1, X2));
                lo = vmin4(lo, vmin4(vmin4(U1, Dn1), vmin4(M1, P1)));
                hi = vmin4(vmin4(sh3(X1, X2), X2), sh1(X2, X3));
                hi = vmin4(hi, vmin4(vmin4(U2, Dn2), vmin4(M2, P2)));
                float eL = __shfl_up(hi.w, 1);
                float eR = __shfl_down(lo.x, 1);
                if (k == 0) {
                    eL = -INFINITY;
                    if (w0 > 0) {
                        float w3 = fminf(fminf(X0.z, X0.w), X1.x);
                        eL = fminf(fminf(w3, fminf(ru[3], rd[3])),
                                   fminf(rm_[3], rp_[3]));
                    }
                }
                if (k == 7) {
                    eR = -INFINITY;
                    if (w0 + 64 < W) {
                        float w3 = fminf(fminf(X2.w, X3.x), X3.y);
                        eR = fminf(fminf(w3, fminf(ru[12], rd[12])),
                                   fminf(rm_[12], rp_[12]));
                    }
                }
                rmlo = vmax4(vmax4(make_float4(eL, lo.x, lo.y, lo.z), lo),
                             make_float4(lo.y, lo.z, lo.w, hi.x));
                rmhi = vmax4(vmax4(make_float4(lo.w, hi.x, hi.y, hi.z), hi),
                             make_float4(hi.y, hi.z, hi.w, eR));
                float* rw = &srm[s & 1][(r + 1) * RSF + 8 * k];
                *(float4*)rw       = rmlo;
                *(float4*)(rw + 4) = rmhi;
            }
            if (tid < 16) {    // halo rows 0 and 33, fully in-thread
                int mr2 = (tid >> 3) ? 33 : 0;
                int k2  = tid & 7;
                int gh2 = h0 - 1 + mr2;
                float4 hlo = NINF4, hhi = NINF4;
                if ((unsigned)gh2 < (unsigned)H) {
                    int xr2 = mr2 + 1;
                    const float* rc  = &xq[xr2 * XSF + 8 * k2];
                    const float* ru  = &xq[(xr2 - 1) * XSF + 8 * k2];
                    const float* rd  = &xq[(xr2 + 1) * XSF + 8 * k2];
                    const float* rm_ = &xm[xr2 * XSF + 8 * k2];
                    const float* rp_ = &xp[xr2 * XSF + 8 * k2];
                    float4 X0 = *(const float4*)rc,        X1 = *(const float4*)(rc + 4),
                           X2 = *(const float4*)(rc + 8),  X3 = *(const float4*)(rc + 12);
                    float4 U1 = *(const float4*)(ru + 4),  U2 = *(const float4*)(ru + 8);
                    float4 Dn1= *(const float4*)(rd + 4),  Dn2= *(const float4*)(rd + 8);
                    float4 M1 = *(const float4*)(rm_ + 4), M2 = *(const float4*)(rm_ + 8);
                    float4 P1 = *(const float4*)(rp_ + 4), P2 = *(const float4*)(rp_ + 8);
                    float4 l2 = vmin4(vmin4(sh3(X0, X1), X1), sh1(X1, X2));
                    l2 = vmin4(l2, vmin4(vmin4(U1, Dn1), vmin4(M1, P1)));
                    float4 g2 = vmin4(vmin4(sh3(X1, X2), X2), sh1(X2, X3));
                    g2 = vmin4(g2, vmin4(vmin4(U2, Dn2), vmin4(M2, P2)));
                    float eL2 = -INFINITY, eR2 = -INFINITY;
                    if (w0 + 8 * k2 - 1 >= 0) {
                        float w3 = fminf(fminf(X0.z, X0.w), X1.x);
                        eL2 = fminf(fminf(w3, fminf(ru[3], rd[3])),
                                    fminf(rm_[3], rp_[3]));
                    }
                    if (w0 + 8 * k2 + 8 < W) {
                        float w3 = fminf(fminf(X2.w, X3.x), X3.y);
                        eR2 = fminf(fminf(w3, fminf(ru[12], rd[12])),
                                    fminf(rm_[12], rp_[12]));
                    }
                    hlo = vmax4(vmax4(make_float4(eL2, l2.x, l2.y, l2.z), l2),
                                make_float4(l2.y, l2.z, l2.w, g2.x));
                    hhi = vmax4(vmax4(make_float4(l2.w, g2.x, g2.y, g2.z), g2),
                                make_float4(g2.y, g2.z, g2.w, eR2));
                }
                float* hw = &srm[s & 1][mr2 * RSF + 8 * k2];
                *(float4*)hw       = hlo;
                *(float4*)(hw + 4) = hhi;
            }
        }

        // ---- xc: x center of plane s-1 (slot (s+3)&3; commit wrote (s+2)&3) ----
        int dm = s - 1;
        float4 xclo = INF4, xchi = INF4;
        if (dm >= gd0 && dm <= gd0 + CD - 1) {
            const float* xd = sx[(dm + 4) & 3];
            xclo = *(const float4*)&xd[(r + 2) * XSF + 8 * k + 4];
            xchi = *(const float4*)&xd[(r + 2) * XSF + 8 * k + 8];
        }

        // ---- H(s-1): hw9 of plane s-1 (rm written last segment + reg row) ----
        float4 hclo = NINF4, hchi = NINF4;
        if (s >= gd0 && dm >= 0 && dm < D) {
            const float* m = srm[dm & 1];
            float4 a0 = *(const float4*)&m[r * RSF + 8 * k];
            float4 a1 = *(const float4*)&m[r * RSF + 8 * k + 4];
            float4 b0 = *(const float4*)&m[(r + 2) * RSF + 8 * k];
            float4 b1 = *(const float4*)&m[(r + 2) * RSF + 8 * k + 4];
            hclo = vmax4(vmax4(a0, rmplo), b0);
            hchi = vmax4(vmax4(a1, rmphi), b1);
        }

        // ---- C(s-2): output d = s-2 (registers only + global) ----
        int d = s - 2;
        if (d >= gd0 && d <= gd0 + CD - 1) {
            float4 mxlo = vmax4(h2lo, vmax4(h1lo, hclo));
            float4 mxhi = vmax4(h2hi, vmax4(h1hi, hchi));
            float4 rlo, rhi;
            rlo.x = fmaxf(xplo.x - (mxlo.x - p2lo.x), 0.0f);
            rlo.y = fmaxf(xplo.y - (mxlo.y - p2lo.y), 0.0f);
            rlo.z = fmaxf(xplo.z - (mxlo.z - p2lo.z), 0.0f);
            rlo.w = fmaxf(xplo.w - (mxlo.w - p2lo.w), 0.0f);
            rhi.x = fmaxf(xphi.x - (mxhi.x - p2hi.x), 0.0f);
            rhi.y = fmaxf(xphi.y - (mxhi.y - p2hi.y), 0.0f);
            rhi.z = fmaxf(xphi.z - (mxhi.z - p2hi.z), 0.0f);
            rhi.w = fmaxf(xphi.w - (mxhi.w - p2hi.w), 0.0f);
            long off = (long)d * HW + (h0 + r) * W + (w0 + 8 * k);
            if constexpr (FINAL) {
                float4 o1 = *(const float4*)(otb + off);
                float4 o2 = *(const float4*)(otb + off + 4);
                s0 += (double)(rlo.x * o1.x) + (double)(rlo.y * o1.y)
                    + (double)(rlo.z * o1.z) + (double)(rlo.w * o1.w)
                    + (double)(rhi.x * o2.x) + (double)(rhi.y * o2.y)
                    + (double)(rhi.z * o2.z) + (double)(rhi.w * o2.w);
                s1 += (double)rlo.x + (double)rlo.y + (double)rlo.z + (double)rlo.w
                    + (double)rhi.x + (double)rhi.y + (double)rhi.z + (double)rhi.w;
            } else {
                *(float4*)(ob + off)     = rlo;
                *(float4*)(ob + off + 4) = rhi;
            }
        }

        // ---- shifts ----
        h2lo = h1lo; h2hi = h1hi; h1lo = hclo; h1hi = hchi;
        p2lo = p1lo; p2hi = p1hi; p1lo = lo;   p1hi = hi;
        rmplo = rmlo; rmphi = rmhi;
        xplo = xclo;  xphi = xchi;

        __syncthreads();   // the ONLY barrier per segment
    }

    if constexpr (FINAL) {
        for (int off = 32; off > 0; off >>= 1) {
            s0 += __shfl_down(s0, off, 64);
            s1 += __shfl_down(s1, off, 64);
        }
        if ((tid & 63) == 0) {
            atomicAdd(&accp[0], s0);
            atomicAdd(&accp[1], s1);
        }
    }
}

__global__ void final_kernel(const double* __restrict__ acc, float* __restrict__ out) {
    double clrecall = (acc[0] + 1e-12) / (acc[1] + 1e-12);
    double clacc    = (acc[2] + 1e-12) / (acc[3] + 1e-12);
    double cldice   = 2.0 * clrecall * clacc / (clrecall + clacc + 1e-12);
    out[0] = (float)(1.0 - cldice);
}

extern "C" void kernel_launch(void* const* d_in, const int* in_sizes, int n_in,
                              void* d_out, int out_size, void* d_ws, size_t ws_size,
                              hipStream_t stream) {
    const float* logits = (const float*)d_in[0];
    const float* target = (const float*)d_in[1];
    const float* mask   = (const float*)d_in[2];
    float* out = (float*)d_out;

    float* pred = (float*)d_ws;
    float* tgt  = pred + NV;
    float* A0   = tgt + NV;
    float* B0   = A0 + NV;

    bool big = ws_size >= (size_t)6 * NV * 4 + 64;
    float* A1   = big ? (B0 + NV) : A0;
    float* B1   = big ? (A1 + NV) : B0;
    double* acc = big ? (double*)(B1 + NV) : (double*)(B0 + NV);

    hipMemsetAsync(acc, 0, 4 * sizeof(double), stream);

    dim3 blk(256);
    prep_kernel<<<dim3(NV / 1024), blk, 0, stream>>>(logits, target, mask, pred, tgt);

    if (big) {
        dim3 g(512);   // 2 tensors x 256 blocks; 2 blocks/CU, all resident
        skel_iter_kernel<false><<<g, blk, 0, stream>>>(tgt, A0, pred, acc, pred, A1, tgt, acc + 2);
        skel_iter_kernel<false><<<g, blk, 0, stream>>>(A0, B0, pred, acc, A1, B1, tgt, acc + 2);
        skel_iter_kernel<false><<<g, blk, 0, stream>>>(B0, A0, pred, acc, B1, A1, tgt, acc + 2);
        skel_iter_kernel<false><<<g, blk, 0, stream>>>(A0, B0, pred, acc, A1, B1, tgt, acc + 2);
        skel_iter_kernel<true ><<<g, blk, 0, stream>>>(B0, nullptr, pred, acc, B1, nullptr, tgt, acc + 2);
    } else {
        dim3 g(256);   // sequential fallback (t = 0 always)
        skel_iter_kernel<false><<<g, blk, 0, stream>>>(tgt, A0, pred, acc, tgt, A0, pred, acc);
        skel_iter_kernel<false><<<g, blk, 0, stream>>>(A0, B0, pred, acc, A0, B0, pred, acc);
        skel_iter_kernel<false><<<g, blk, 0, stream>>>(B0, A0, pred, acc, B0, A0, pred, acc);
        skel_iter_kernel<false><<<g, blk, 0, stream>>>(A0, B0, pred, acc, A0, B0, pred, acc);
        skel_iter_kernel<true ><<<g, blk, 0, stream>>>(B0, nullptr, pred, acc, B0, nullptr, pred, acc);
        skel_iter_kernel<false><<<g, blk, 0, stream>>>(pred, A0, tgt, acc + 2, pred, A0, tgt, acc + 2);
        skel_iter_kernel<false><<<g, blk, 0, stream>>>(A0, B0, tgt, acc + 2, A0, B0, tgt, acc + 2);
        skel_iter_kernel<false><<<g, blk, 0, stream>>>(B0, A0, tgt, acc + 2, B0, A0, tgt, acc + 2);
        skel_iter_kernel<false><<<g, blk, 0, stream>>>(A0, B0, tgt, acc + 2, A0, B0, tgt, acc + 2);
        skel_iter_kernel<true ><<<g, blk, 0, stream>>>(B0, nullptr, tgt, acc + 2, B0, nullptr, tgt, acc + 2);
    }

    final_kernel<<<1, 1, 0, stream>>>(acc, out);
}